// Round 8
// baseline (79.382 us; speedup 1.0000x reference)
//
#include <hip/hip_runtime.h>

namespace {
constexpr int N   = 64;
constexpr int D   = 32;
constexpr int PD  = 36;   // padded ind row (dwords): measured conflict-free (r1/r2)
constexpr int SHP = 72;   // sh row pad: 72%32==8 conflict-free residue (r11-r17)
constexpr float LOG2E = 1.4426950408889634f;
constexpr float LN2   = 0.6931471805599453f;

typedef float f32x2 __attribute__((ext_vector_type(2)));

#if __has_builtin(__builtin_amdgcn_exp2f)
__device__ __forceinline__ float fexp2(float x) { return __builtin_amdgcn_exp2f(x); }
#else
__device__ __forceinline__ float fexp2(float x) { return exp2f(x); }
#endif
#if __has_builtin(__builtin_amdgcn_rcpf)
__device__ __forceinline__ float frcp(float x) { return __builtin_amdgcn_rcpf(x); }
#else
__device__ __forceinline__ float frcp(float x) { return 1.0f / x; }
#endif
__device__ __forceinline__ void wavebar() {
#if __has_builtin(__builtin_amdgcn_wave_barrier)
    __builtin_amdgcn_wave_barrier();
#endif
}

// r24: SECOND MICRO PASS (r23 base, best @78.37). r23 proved score is
// issue-slot-bound: -2 slots/h-iter bought -1.2us (~0.55us/slot). This round
// mines the same vein:
//  1. mn-fusion: aneg = amv*NEGA; mn = aneg+bneg  ->  mn = fma(amv,NEGA,bneg)
//     (aneg had no other use; 2 ops -> 1; 1-ulp mn change, tolerance-safe)
//  2. post-exp chain 2->1: AB = A*B issues DURING the exp's trans latency
//     (independent of E), then acc = fma(E, AB, acc). Same count, shorter
//     dependency tail (attacks the stall component on top of pure issue).
// SCORE_BODY now 8 pk + 2 trans per h-iter (was 9+2; r14 original was 11+2).
// Everything else r23 verbatim (max-elim, setprio window, phase structure).
// Pre-commit: null (>=78.2) -> fusion vein empty -> ROOFLINE next round.
__global__ __launch_bounds__(512, 4) void fused(
        const float* __restrict__ feature,
        const float* __restrict__ ind,
        float* __restrict__ out) {
    __shared__ float ind_lds[3][N][PD];   // 27648 B
    __shared__ float s_lds[3][N];         //   768 B
    __shared__ float sh_lds[N][SHP];      // 18432 B   total 46848 B -> 2 blocks/CU

    const int t    = threadIdx.x;
    const int lane = t & 63;
    const int wave = t >> 6;
    const int b    = blockIdx.x;

    // ---- stage indicator: 1536 float4, 3 per thread, coalesced ----
    {
        const float4* src = reinterpret_cast<const float4*>(ind);
#pragma unroll
        for (int idx = t; idx < 3 * N * D / 4; idx += 512) {
            int a = idx >> 9;
            int r = idx & 511;
            int n = r >> 3;
            int k = r & 7;
            *reinterpret_cast<float4*>(&ind_lds[a][n][k * 4]) = src[idx];
        }
    }

    // ---- s[a][n] = feature[b,n,:] . ind[a,n,:] from GLOBAL, overlapped with
    //      staging (single barrier; r13-verified) ----
    if (t < 3 * N) {
        int a = t >> 6, n = t & 63;
        const float4* frow = reinterpret_cast<const float4*>(feature + ((size_t)b * N + n) * D);
        const float4* irow = reinterpret_cast<const float4*>(ind + (a * N + n) * D);
        f32x2 sa2 = {0.f, 0.f};
#pragma unroll
        for (int k = 0; k < 8; ++k) {
            float4 f4 = frow[k];
            float4 i4 = irow[k];
            sa2 = __builtin_elementwise_fma(f32x2{f4.x, f4.y}, f32x2{i4.x, i4.y}, sa2);
            sa2 = __builtin_elementwise_fma(f32x2{f4.z, f4.w}, f32x2{i4.z, i4.w}, sa2);
        }
        s_lds[a][n] = sa2.x + sa2.y;
    }
    __syncthreads();   // the ONLY block barrier

    // wave-uniform row indices (readfirstlane -> SGPR -> s_load addresses)
    int igu[8];
#pragma unroll
    for (int r = 0; r < 8; ++r)
        igu[r] = __builtin_amdgcn_readfirstlane(wave * 8 + r);

    // ---- gate bitmasks: w-row (ind1[lane]) in VGPRs, a-rows via SCALAR loads
    //      from global ind0 (wave-uniform addr) -> s_load, SGPR operands ----
    unsigned long long gmask[8];
    {
        f32x2 wv[16];
#pragma unroll
        for (int k4 = 0; k4 < 8; ++k4) {
            float4 w4 = *reinterpret_cast<const float4*>(&ind_lds[1][lane][k4 * 4]);
            wv[k4 * 2 + 0] = f32x2{w4.x, w4.y};
            wv[k4 * 2 + 1] = f32x2{w4.z, w4.w};
        }
#pragma unroll
        for (int r = 0; r < 8; ++r) {
            f32x2 ga = {0.f, 0.f};
#pragma unroll
            for (int k4 = 0; k4 < 8; ++k4) {
                float4 a4 = *reinterpret_cast<const float4*>(ind + igu[r] * D + k4 * 4);  // s_load
                ga = __builtin_elementwise_fma(f32x2{a4.x, a4.y}, wv[k4 * 2 + 0], ga);
                ga = __builtin_elementwise_fma(f32x2{a4.z, a4.w}, wv[k4 * 2 + 1], ga);
            }
            gmask[r] = __ballot(ga.x + ga.y > 0.f);
        }
    }

    const float s1Ls = s_lds[1][lane] * LOG2E;
    const f32x2 s1L  = {s1Ls, s1Ls};
    const f32x2 ln2v = {LN2, LN2};
    const f32x2 onev = {1.0f, 1.0f};
    const f32x2 zerv = {0.0f, 0.0f};

    // ---- hoisted row scalars ----
    float s0v[8];
#pragma unroll
    for (int r = 0; r < 8; ++r) s0v[r] = s_lds[0][wave * 8 + r] * LOG2E;

    // ---- score: sign-split packed loop, 2 chunks of 16 d-elements (r14);
    //      v4 rows via SCALAR loads from global ind1 (wave-uniform addr).
    //      T5: raise wave priority for the whole score section (r23, +). ----
#if __has_builtin(__builtin_amdgcn_s_setprio)
    __builtin_amdgcn_s_setprio(1);
#endif
    f32x2 sc2[8] = {{0.f, 0.f}, {0.f, 0.f}, {0.f, 0.f}, {0.f, 0.f},
                    {0.f, 0.f}, {0.f, 0.f}, {0.f, 0.f}, {0.f, 0.f}};

#define SCORE_BODY(NEGA, FMAA, AM, FM)                                              \
    {                                                                               \
        const f32x2 amv = {(AM), (AM)};                                             \
        const f32x2 fmv = {(FM), (FM)};                                             \
        f32x2 acc = sc2[r];                                                         \
        _Pragma("unroll")                                                           \
        for (int k4 = 0; k4 < 4; ++k4) {                                            \
            float4 v4 = *reinterpret_cast<const float4*>(                           \
                ind + N * D + igu[r] * D + c * 16 + k4 * 4);   /* s_load */         \
            f32x2 vp[2] = {f32x2{v4.x, v4.y}, f32x2{v4.z, v4.w}};                   \
            _Pragma("unroll")                                                       \
            for (int h = 0; h < 2; ++h) {                                           \
                f32x2 A    = __builtin_elementwise_fma(fmv, FMAA[k4 * 2 + h], onev);\
                f32x2 bL   = s1L * vp[h];                                           \
                f32x2 bneg = __builtin_elementwise_min(bL, zerv);                   \
                /* max(bL,0) = bL - bneg (r23, bit-exact) */                        \
                f32x2 B    = __builtin_elementwise_fma(bL - bneg, ln2v, onev);      \
                /* AB independent of E: issues under the exp's trans latency */     \
                f32x2 AB   = A * B;                                                 \
                /* r24 fusion: mn = fma(amv, NEGA, bneg)  (was mul+add) */          \
                f32x2 mn   = __builtin_elementwise_fma(amv, NEGA[k4 * 2 + h], bneg);\
                f32x2 E    = {fexp2(mn.x), fexp2(mn.y)};                            \
                acc = __builtin_elementwise_fma(E, AB, acc);                        \
            }                                                                       \
        }                                                                           \
        sc2[r] = acc;                                                               \
    }

#pragma unroll
    for (int c = 0; c < 2; ++c) {
        // per-chunk precompute: un = min(u,0), upl = max(u,0)*ln2  (16 f32x2 live)
        f32x2 un[8], upl[8];
#pragma unroll
        for (int k4 = 0; k4 < 4; ++k4) {
            float4 v = *reinterpret_cast<const float4*>(&ind_lds[0][lane][c * 16 + k4 * 4]);
            f32x2 x0 = {v.x, v.y}, x1 = {v.z, v.w};
            f32x2 n0 = __builtin_elementwise_min(x0, zerv);
            f32x2 n1 = __builtin_elementwise_min(x1, zerv);
            un[k4 * 2 + 0]  = n0;
            un[k4 * 2 + 1]  = n1;
            upl[k4 * 2 + 0] = (x0 - n0) * ln2v;
            upl[k4 * 2 + 1] = (x1 - n1) * ln2v;
        }
#pragma unroll
        for (int r = 0; r < 8; ++r) {
            // force wave-uniform scalar: s_cmp + s_cbranch, zero divergence
            const float s0u = __uint_as_float(
                __builtin_amdgcn_readfirstlane(__float_as_uint(s0v[r])));
            if (s0u >= 0.f) {
                SCORE_BODY(un, upl, s0u, s0u)
            } else {
                SCORE_BODY(upl, un, s0u * LOG2E, s0u * LN2)
            }
        }
    }
#undef SCORE_BODY
#if __has_builtin(__builtin_amdgcn_s_setprio)
    __builtin_amdgcn_s_setprio(0);
#endif

    float score[8];
#pragma unroll
    for (int r = 0; r < 8; ++r) score[r] = sc2[r].x + sc2[r].y;

    // ---- 8-way-ILP wave softmax over j (64 lanes) ----
    float mx[8], e[8], sm[8];
#pragma unroll
    for (int r = 0; r < 8; ++r) mx[r] = score[r];
#pragma unroll
    for (int off = 32; off >= 1; off >>= 1) {
#pragma unroll
        for (int r = 0; r < 8; ++r) mx[r] = fmaxf(mx[r], __shfl_xor(mx[r], off));
    }
#pragma unroll
    for (int r = 0; r < 8; ++r) e[r] = fexp2((score[r] - mx[r]) * LOG2E);
#pragma unroll
    for (int r = 0; r < 8; ++r) sm[r] = e[r];
#pragma unroll
    for (int off = 32; off >= 1; off >>= 1) {
#pragma unroll
        for (int r = 0; r < 8; ++r) sm[r] += __shfl_xor(sm[r], off);
    }
#pragma unroll
    for (int r = 0; r < 8; ++r) {
        const int ig  = wave * 8 + r;
        const float g = (float)((gmask[r] >> lane) & 1ull);
        sh_lds[ig][lane] = (e[r] * g) * (s_lds[2][ig] * frcp(sm[r]));
    }

    // NO block barrier: wave w wrote sh rows 8w..8w+7 and phase 2's thread t
    // (row t>>3) reads only those rows (same-wave LDS RAW, lgkmcnt-ordered;
    // r13/r14/r17-verified pattern).
    wavebar();

    // ---- phase 2: out[i,:] = sh[i,:] @ ind2; thread = (i_loc, d-quad) ----
    {
        const int i_loc = t >> 3;
        const int dq    = t & 7;
        f32x2 acc0 = {0.f, 0.f}, acc1 = {0.f, 0.f};
#pragma unroll
        for (int j = 0; j < 64; j += 4) {
            float4 sh4 = *reinterpret_cast<const float4*>(&sh_lds[i_loc][j]);
#pragma unroll
            for (int c = 0; c < 4; ++c) {
                float4 v4 = *reinterpret_cast<const float4*>(&ind_lds[2][j + c][dq * 4]);
                float  w  = (&sh4.x)[c];
                f32x2 wvv = {w, w};
                acc0 = __builtin_elementwise_fma(wvv, f32x2{v4.x, v4.y}, acc0);
                acc1 = __builtin_elementwise_fma(wvv, f32x2{v4.z, v4.w}, acc1);
            }
        }
        float4 acc = {acc0.x, acc0.y, acc1.x, acc1.y};
        *reinterpret_cast<float4*>(out + ((size_t)b * N + i_loc) * D + dq * 4) = acc;
    }
}
}  // namespace

extern "C" void kernel_launch(void* const* d_in, const int* in_sizes, int n_in,
                              void* d_out, int out_size, void* d_ws, size_t ws_size,
                              hipStream_t stream) {
    const float* feature = (const float*)d_in[0];
    const float* ind     = (const float*)d_in[1];
    float*       out     = (float*)d_out;
    fused<<<512, 512, 0, stream>>>(feature, ind, out);
}

// Round 9
// 78.242 us; speedup vs baseline: 1.0146x; 1.0146x over previous
//
#include <hip/hip_runtime.h>

namespace {
constexpr int N   = 64;
constexpr int D   = 32;
constexpr int PD  = 36;   // padded ind row (dwords): measured conflict-free (r1/r2)
constexpr int SHP = 72;   // sh row pad: 72%32==8 conflict-free residue (r11-r17)
constexpr float LOG2E = 1.4426950408889634f;
constexpr float LN2   = 0.6931471805599453f;

typedef float f32x2 __attribute__((ext_vector_type(2)));

#if __has_builtin(__builtin_amdgcn_exp2f)
__device__ __forceinline__ float fexp2(float x) { return __builtin_amdgcn_exp2f(x); }
#else
__device__ __forceinline__ float fexp2(float x) { return exp2f(x); }
#endif
#if __has_builtin(__builtin_amdgcn_rcpf)
__device__ __forceinline__ float frcp(float x) { return __builtin_amdgcn_rcpf(x); }
#else
__device__ __forceinline__ float frcp(float x) { return 1.0f / x; }
#endif
__device__ __forceinline__ void wavebar() {
#if __has_builtin(__builtin_amdgcn_wave_barrier)
    __builtin_amdgcn_wave_barrier();
#endif
}

// r25: REVERT to r23 (verified best, 78.37us). r24's two edits (mn-fusion,
// AB-reorder) regressed to 79.38 + absmax 0.25: the fma-fusion chained mn
// behind the vp s_load (was: aneg independent, early-issueable) -> net loss
// in a latency-limited loop. Lesson: in stall-bound code, op COUNT matters
// less than op INDEPENDENCE; r23's form keeps aneg off the load chain.
// Final cost map (r20-r24): dur 78.4 = 40.6 fill (harness) + 7.4 gap
// (harness) + ~30.4 fused; fused = ~13.5 score at issue/latency floor +
// ~17 distributed latency robust to 7 structural attacks (occupancy x3,
// work-halving x2, load-pipelining, LDS-cut). r23 levers retained:
//  1. B-side max elimination: max(bL,0) = bL - min(bL,0) (bit-exact)
//  2. T5 s_setprio(1) around score
// Pre-commit: this restore lands ~78.4 -> ROOFLINE declared next round.
__global__ __launch_bounds__(512, 4) void fused(
        const float* __restrict__ feature,
        const float* __restrict__ ind,
        float* __restrict__ out) {
    __shared__ float ind_lds[3][N][PD];   // 27648 B
    __shared__ float s_lds[3][N];         //   768 B
    __shared__ float sh_lds[N][SHP];      // 18432 B   total 46848 B -> 2 blocks/CU

    const int t    = threadIdx.x;
    const int lane = t & 63;
    const int wave = t >> 6;
    const int b    = blockIdx.x;

    // ---- stage indicator: 1536 float4, 3 per thread, coalesced ----
    {
        const float4* src = reinterpret_cast<const float4*>(ind);
#pragma unroll
        for (int idx = t; idx < 3 * N * D / 4; idx += 512) {
            int a = idx >> 9;
            int r = idx & 511;
            int n = r >> 3;
            int k = r & 7;
            *reinterpret_cast<float4*>(&ind_lds[a][n][k * 4]) = src[idx];
        }
    }

    // ---- s[a][n] = feature[b,n,:] . ind[a,n,:] from GLOBAL, overlapped with
    //      staging (single barrier; r13-verified) ----
    if (t < 3 * N) {
        int a = t >> 6, n = t & 63;
        const float4* frow = reinterpret_cast<const float4*>(feature + ((size_t)b * N + n) * D);
        const float4* irow = reinterpret_cast<const float4*>(ind + (a * N + n) * D);
        f32x2 sa2 = {0.f, 0.f};
#pragma unroll
        for (int k = 0; k < 8; ++k) {
            float4 f4 = frow[k];
            float4 i4 = irow[k];
            sa2 = __builtin_elementwise_fma(f32x2{f4.x, f4.y}, f32x2{i4.x, i4.y}, sa2);
            sa2 = __builtin_elementwise_fma(f32x2{f4.z, f4.w}, f32x2{i4.z, i4.w}, sa2);
        }
        s_lds[a][n] = sa2.x + sa2.y;
    }
    __syncthreads();   // the ONLY block barrier

    // wave-uniform row indices (readfirstlane -> SGPR -> s_load addresses)
    int igu[8];
#pragma unroll
    for (int r = 0; r < 8; ++r)
        igu[r] = __builtin_amdgcn_readfirstlane(wave * 8 + r);

    // ---- gate bitmasks: w-row (ind1[lane]) in VGPRs, a-rows via SCALAR loads
    //      from global ind0 (wave-uniform addr) -> s_load, SGPR operands ----
    unsigned long long gmask[8];
    {
        f32x2 wv[16];
#pragma unroll
        for (int k4 = 0; k4 < 8; ++k4) {
            float4 w4 = *reinterpret_cast<const float4*>(&ind_lds[1][lane][k4 * 4]);
            wv[k4 * 2 + 0] = f32x2{w4.x, w4.y};
            wv[k4 * 2 + 1] = f32x2{w4.z, w4.w};
        }
#pragma unroll
        for (int r = 0; r < 8; ++r) {
            f32x2 ga = {0.f, 0.f};
#pragma unroll
            for (int k4 = 0; k4 < 8; ++k4) {
                float4 a4 = *reinterpret_cast<const float4*>(ind + igu[r] * D + k4 * 4);  // s_load
                ga = __builtin_elementwise_fma(f32x2{a4.x, a4.y}, wv[k4 * 2 + 0], ga);
                ga = __builtin_elementwise_fma(f32x2{a4.z, a4.w}, wv[k4 * 2 + 1], ga);
            }
            gmask[r] = __ballot(ga.x + ga.y > 0.f);
        }
    }

    const float s1Ls = s_lds[1][lane] * LOG2E;
    const f32x2 s1L  = {s1Ls, s1Ls};
    const f32x2 ln2v = {LN2, LN2};
    const f32x2 onev = {1.0f, 1.0f};
    const f32x2 zerv = {0.0f, 0.0f};

    // ---- hoisted row scalars ----
    float s0v[8];
#pragma unroll
    for (int r = 0; r < 8; ++r) s0v[r] = s_lds[0][wave * 8 + r] * LOG2E;

    // ---- score: sign-split packed loop, 2 chunks of 16 d-elements (r14);
    //      v4 rows via SCALAR loads from global ind1 (wave-uniform addr).
    //      T5: raise wave priority for the whole score section. ----
#if __has_builtin(__builtin_amdgcn_s_setprio)
    __builtin_amdgcn_s_setprio(1);
#endif
    f32x2 sc2[8] = {{0.f, 0.f}, {0.f, 0.f}, {0.f, 0.f}, {0.f, 0.f},
                    {0.f, 0.f}, {0.f, 0.f}, {0.f, 0.f}, {0.f, 0.f}};

#define SCORE_BODY(NEGA, FMAA, AM, FM)                                              \
    {                                                                               \
        const f32x2 amv = {(AM), (AM)};                                             \
        const f32x2 fmv = {(FM), (FM)};                                             \
        f32x2 acc = sc2[r];                                                         \
        _Pragma("unroll")                                                           \
        for (int k4 = 0; k4 < 4; ++k4) {                                            \
            float4 v4 = *reinterpret_cast<const float4*>(                           \
                ind + N * D + igu[r] * D + c * 16 + k4 * 4);   /* s_load */         \
            f32x2 vp[2] = {f32x2{v4.x, v4.y}, f32x2{v4.z, v4.w}};                   \
            _Pragma("unroll")                                                       \
            for (int h = 0; h < 2; ++h) {                                           \
                f32x2 aneg = amv * NEGA[k4 * 2 + h];                                \
                f32x2 A    = __builtin_elementwise_fma(fmv, FMAA[k4 * 2 + h], onev);\
                f32x2 bL   = s1L * vp[h];                                           \
                f32x2 bneg = __builtin_elementwise_min(bL, zerv);                   \
                /* max(bL,0) = bL - bneg: bit-exact, kills the v_max pair */        \
                f32x2 B    = __builtin_elementwise_fma(bL - bneg, ln2v, onev);      \
                f32x2 mn   = aneg + bneg;                                           \
                f32x2 E    = {fexp2(mn.x), fexp2(mn.y)};                            \
                acc = __builtin_elementwise_fma(E * A, B, acc);                     \
            }                                                                       \
        }                                                                           \
        sc2[r] = acc;                                                               \
    }

#pragma unroll
    for (int c = 0; c < 2; ++c) {
        // per-chunk precompute: un = min(u,0), upl = max(u,0)*ln2  (16 f32x2 live)
        f32x2 un[8], upl[8];
#pragma unroll
        for (int k4 = 0; k4 < 4; ++k4) {
            float4 v = *reinterpret_cast<const float4*>(&ind_lds[0][lane][c * 16 + k4 * 4]);
            f32x2 x0 = {v.x, v.y}, x1 = {v.z, v.w};
            f32x2 n0 = __builtin_elementwise_min(x0, zerv);
            f32x2 n1 = __builtin_elementwise_min(x1, zerv);
            un[k4 * 2 + 0]  = n0;
            un[k4 * 2 + 1]  = n1;
            upl[k4 * 2 + 0] = (x0 - n0) * ln2v;
            upl[k4 * 2 + 1] = (x1 - n1) * ln2v;
        }
#pragma unroll
        for (int r = 0; r < 8; ++r) {
            // force wave-uniform scalar: s_cmp + s_cbranch, zero divergence
            const float s0u = __uint_as_float(
                __builtin_amdgcn_readfirstlane(__float_as_uint(s0v[r])));
            if (s0u >= 0.f) {
                SCORE_BODY(un, upl, s0u, s0u)
            } else {
                SCORE_BODY(upl, un, s0u * LOG2E, s0u * LN2)
            }
        }
    }
#undef SCORE_BODY
#if __has_builtin(__builtin_amdgcn_s_setprio)
    __builtin_amdgcn_s_setprio(0);
#endif

    float score[8];
#pragma unroll
    for (int r = 0; r < 8; ++r) score[r] = sc2[r].x + sc2[r].y;

    // ---- 8-way-ILP wave softmax over j (64 lanes) ----
    float mx[8], e[8], sm[8];
#pragma unroll
    for (int r = 0; r < 8; ++r) mx[r] = score[r];
#pragma unroll
    for (int off = 32; off >= 1; off >>= 1) {
#pragma unroll
        for (int r = 0; r < 8; ++r) mx[r] = fmaxf(mx[r], __shfl_xor(mx[r], off));
    }
#pragma unroll
    for (int r = 0; r < 8; ++r) e[r] = fexp2((score[r] - mx[r]) * LOG2E);
#pragma unroll
    for (int r = 0; r < 8; ++r) sm[r] = e[r];
#pragma unroll
    for (int off = 32; off >= 1; off >>= 1) {
#pragma unroll
        for (int r = 0; r < 8; ++r) sm[r] += __shfl_xor(sm[r], off);
    }
#pragma unroll
    for (int r = 0; r < 8; ++r) {
        const int ig  = wave * 8 + r;
        const float g = (float)((gmask[r] >> lane) & 1ull);
        sh_lds[ig][lane] = (e[r] * g) * (s_lds[2][ig] * frcp(sm[r]));
    }

    // NO block barrier: wave w wrote sh rows 8w..8w+7 and phase 2's thread t
    // (row t>>3) reads only those rows (same-wave LDS RAW, lgkmcnt-ordered;
    // r13/r14/r17-verified pattern).
    wavebar();

    // ---- phase 2: out[i,:] = sh[i,:] @ ind2; thread = (i_loc, d-quad) ----
    {
        const int i_loc = t >> 3;
        const int dq    = t & 7;
        f32x2 acc0 = {0.f, 0.f}, acc1 = {0.f, 0.f};
#pragma unroll
        for (int j = 0; j < 64; j += 4) {
            float4 sh4 = *reinterpret_cast<const float4*>(&sh_lds[i_loc][j]);
#pragma unroll
            for (int c = 0; c < 4; ++c) {
                float4 v4 = *reinterpret_cast<const float4*>(&ind_lds[2][j + c][dq * 4]);
                float  w  = (&sh4.x)[c];
                f32x2 wvv = {w, w};
                acc0 = __builtin_elementwise_fma(wvv, f32x2{v4.x, v4.y}, acc0);
                acc1 = __builtin_elementwise_fma(wvv, f32x2{v4.z, v4.w}, acc1);
            }
        }
        float4 acc = {acc0.x, acc0.y, acc1.x, acc1.y};
        *reinterpret_cast<float4*>(out + ((size_t)b * N + i_loc) * D + dq * 4) = acc;
    }
}
}  // namespace

extern "C" void kernel_launch(void* const* d_in, const int* in_sizes, int n_in,
                              void* d_out, int out_size, void* d_ws, size_t ws_size,
                              hipStream_t stream) {
    const float* feature = (const float*)d_in[0];
    const float* ind     = (const float*)d_in[1];
    float*       out     = (float*)d_out;
    fused<<<512, 512, 0, stream>>>(feature, ind, out);
}